// Round 1
// baseline (203.304 us; speedup 1.0000x reference)
//
#include <hip/hip_runtime.h>

// Panorama: warp frame (4,1080,1920) via homography into canvas (4,2048,3072),
// alpha-over composite. All float32.
//
// sx = (adj(H)·p).x / (adj(H)·p).z  — the 1/det of inv(H) cancels in the ratio.

#define FH 1080
#define FW 1920
#define CH 2048
#define CW 3072
#define FHW (FH * FW)
#define CHW (CH * CW)

__global__ __launch_bounds__(256) void pano_kernel(
    const float* __restrict__ frame,
    const float* __restrict__ Hm,
    const float* __restrict__ canvas,
    float* __restrict__ out)
{
    const int x = blockIdx.x * 256 + threadIdx.x;   // CW == 3072 == 12*256
    const int y = blockIdx.y;
    const int pix = y * CW + x;

    // H entries (uniform loads; compiler scalarizes)
    const float a  = Hm[0], b  = Hm[1], c  = Hm[2];
    const float d  = Hm[3], e  = Hm[4], f  = Hm[5];
    const float g  = Hm[6], hh = Hm[7], i9 = Hm[8];

    // adjugate rows (det cancels in the perspective divide)
    const float A0 = e * i9 - f * hh, A1 = c * hh - b * i9, A2 = b * f - c * e;
    const float B0 = f * g  - d * i9, B1 = a * i9 - c * g,  B2 = c * d - a * f;
    const float C0 = d * hh - e * g,  C1 = b * g  - a * hh, C2 = a * e - b * d;

    const float xf = (float)x, yf = (float)y;
    const float u = A0 * xf + A1 * yf + A2;
    const float v = B0 * xf + B1 * yf + B2;
    const float w = C0 * xf + C1 * yf + C2;
    const float sx = u / w;
    const float sy = v / w;

    const float x0f = floorf(sx);
    const float y0f = floorf(sy);
    const float wx = sx - x0f;
    const float wy = sy - y0f;
    const int x0 = (int)x0f;
    const int y0 = (int)y0f;

    // canvas (rgb + alpha)
    const float c0 = canvas[0 * CHW + pix];
    const float c1 = canvas[1 * CHW + pix];
    const float c2 = canvas[2 * CHW + pix];
    const float ac = canvas[3 * CHW + pix];

    float w0 = 0.f, w1 = 0.f, w2 = 0.f, as = 0.f;

    // any of the 4 taps in-bounds?
    if (x0 >= -1 && x0 <= FW - 1 && y0 >= -1 && y0 <= FH - 1) {
        const int x1 = x0 + 1, y1 = y0 + 1;
        const float mx0 = (x0 >= 0 && x0 <= FW - 1) ? 1.f : 0.f;
        const float mx1 = (x1 >= 0 && x1 <= FW - 1) ? 1.f : 0.f;
        const float my0 = (y0 >= 0 && y0 <= FH - 1) ? 1.f : 0.f;
        const float my1 = (y1 >= 0 && y1 <= FH - 1) ? 1.f : 0.f;
        const int xc0 = min(max(x0, 0), FW - 1);
        const int xc1 = min(max(x1, 0), FW - 1);
        const int yc0 = min(max(y0, 0), FH - 1);
        const int yc1 = min(max(y1, 0), FH - 1);

        const float w00 = (1.f - wx) * (1.f - wy) * mx0 * my0;
        const float w01 = wx * (1.f - wy) * mx1 * my0;
        const float w10 = (1.f - wx) * wy * mx0 * my1;
        const float w11 = wx * wy * mx1 * my1;

        const int i00 = yc0 * FW + xc0;
        const int i01 = yc0 * FW + xc1;
        const int i10 = yc1 * FW + xc0;
        const int i11 = yc1 * FW + xc1;

        #pragma unroll
        for (int ch = 0; ch < 4; ++ch) {
            const float* fp = frame + ch * FHW;
            const float val = w00 * fp[i00] + w01 * fp[i01]
                            + w10 * fp[i10] + w11 * fp[i11];
            if (ch == 0) w0 = val;
            else if (ch == 1) w1 = val;
            else if (ch == 2) w2 = val;
            else as = val;
        }
    }

    const float k = ac * (1.f - as);
    out[0 * CHW + pix] = w0 * as + c0 * k;
    out[1 * CHW + pix] = w1 * as + c1 * k;
    out[2 * CHW + pix] = w2 * as + c2 * k;
    out[3 * CHW + pix] = as + k;
}

extern "C" void kernel_launch(void* const* d_in, const int* in_sizes, int n_in,
                              void* d_out, int out_size, void* d_ws, size_t ws_size,
                              hipStream_t stream) {
    const float* frame  = (const float*)d_in[0];
    const float* Hm     = (const float*)d_in[1];
    const float* canvas = (const float*)d_in[2];
    float* out = (float*)d_out;

    dim3 block(256, 1, 1);
    dim3 grid(CW / 256, CH, 1);
    pano_kernel<<<grid, block, 0, stream>>>(frame, Hm, canvas, out);
}